// Round 8
// baseline (784.921 us; speedup 1.0000x reference)
//
#include <hip/hip_runtime.h>

// SoftTopK: x (8,1024,256) f32, noise (8,1024,8,256) f32
// perturbed = x + noise*1e-4 ; idx = smallest-16 indices (stable) per (b,n,s)
// out (8,1024,16,256) f32 = one_hot(idx).mean over s
//
// Block = 128 threads = 2 waves = one (b,n) row. Each wave holds 4 samples
// in 16-lane groups; each lane owns 16 elements of its group's sample as
// packed u64 keys (mono(value)<<32 | m). m is unique per sample, so u64
// order == lax.top_k's stable (value asc, index asc) order, exactly.
// Per lane: Batcher odd-even mergesort (63 CE, fully unrolled, static
// register indices). Per round: head k[0] is the lane min (free); 4-level
// DPP u64-min over the 16-lane group (xor1, xor2, half_mirror=xor7,
// mirror=xor15 -- all row-local) gives the group min to all lanes WITH its
// index in the low bits -- no ballot/ffs/readlane; winner shift-pops its
// sorted list (static cndmask shift). Rank r's index is captured by lane
// i==r. Output: block zeroes its 16 KiB row up front (overlaps load
// latency), then fence + barrier + one global f32 atomicAdd per (rank,
// sample). __fadd_rn/__fmul_rn forbid FMA contraction so perturbed values
// bit-match the fp32 reference.

#define TOPK 16
#define NSAMP 8
#define MDIM 256
#define BN_TOTAL 8192

typedef unsigned long long u64;
typedef unsigned int u32;

__device__ __forceinline__ u32 mono(float v) {
  u32 b = __float_as_uint(v);
  // monotone map: ascending u <=> ascending v (total order)
  return (b & 0x80000000u) ? ~b : (b | 0x80000000u);
}

template <int CTRL>
__device__ __forceinline__ u64 dpp_min_u64(u64 v) {
  const int lo = (int)(u32)v;
  const int hi = (int)(u32)(v >> 32);
  const int olo = __builtin_amdgcn_update_dpp(lo, lo, CTRL, 0xF, 0xF, false);
  const int ohi = __builtin_amdgcn_update_dpp(hi, hi, CTRL, 0xF, 0xF, false);
  const u64 o = ((u64)(u32)ohi << 32) | (u32)olo;
  return o < v ? o : v;
}

__global__ __launch_bounds__(128, 6) void soft_topk_kernel(
    const float* __restrict__ x, const float* __restrict__ noise,
    float* __restrict__ out) {
  const int bn = blockIdx.x;
  const int tid = threadIdx.x;
  const int wave = tid >> 6;
  const int lane = tid & 63;
  const int g = lane >> 4;     // 16-lane group within wave
  const int i = lane & 15;     // lane in group == output rank it captures
  const int s = wave * 4 + g;  // sample 0..7
  const int mb = i * 16;       // first element index owned by this lane

  float* const orow = out + (size_t)bn * (TOPK * MDIM);

  // ---- zero the output row (16 KiB) early; overlaps input-load latency ----
  float4* const outv = reinterpret_cast<float4*>(orow);
  const float4 z4 = make_float4(0.f, 0.f, 0.f, 0.f);
#pragma unroll
  for (int j = 0; j < 8; ++j) outv[tid + 128 * j] = z4;

  // ---- build 16 packed keys: (mono(x + noise*sigma) << 32) | m ----
  u64 k[16];
  const float* xr = x + (size_t)bn * MDIM + mb;
  const float* nr = noise + ((size_t)bn * NSAMP + s) * MDIM + mb;
#pragma unroll
  for (int c = 0; c < 4; ++c) {
    const float4 x4 = *reinterpret_cast<const float4*>(xr + 4 * c);
    const float4 n4 = *reinterpret_cast<const float4*>(nr + 4 * c);
    k[4 * c + 0] = ((u64)mono(__fadd_rn(x4.x, __fmul_rn(n4.x, 1e-4f))) << 32) |
                   (u32)(mb + 4 * c + 0);
    k[4 * c + 1] = ((u64)mono(__fadd_rn(x4.y, __fmul_rn(n4.y, 1e-4f))) << 32) |
                   (u32)(mb + 4 * c + 1);
    k[4 * c + 2] = ((u64)mono(__fadd_rn(x4.z, __fmul_rn(n4.z, 1e-4f))) << 32) |
                   (u32)(mb + 4 * c + 2);
    k[4 * c + 3] = ((u64)mono(__fadd_rn(x4.w, __fmul_rn(n4.w, 1e-4f))) << 32) |
                   (u32)(mb + 4 * c + 3);
  }

  // ---- per-lane Batcher odd-even mergesort, n=16 (63 CE, fully unrolled;
  //      all indices compile-time constants -> stays in registers) ----
#pragma unroll
  for (int p = 1; p < 16; p <<= 1) {
#pragma unroll
    for (int kk = p; kk >= 1; kk >>= 1) {
#pragma unroll
      for (int j = kk % p; j + kk < 16; j += 2 * kk) {
#pragma unroll
        for (int ii = 0; ii < kk; ++ii) {
          if (ii + j + kk < 16) {
            if ((ii + j) / (2 * p) == (ii + j + kk) / (2 * p)) {
              const int a = ii + j, b = ii + j + kk;
              const u64 lo = k[a] < k[b] ? k[a] : k[b];
              const u64 hi = k[a] < k[b] ? k[b] : k[a];
              k[a] = lo;
              k[b] = hi;
            }
          }
        }
      }
    }
  }

  // ---- 16 extraction rounds: DPP group-min of heads, shift-pop winner ----
  u32 cap = 0;  // m captured by lane i == rank
#pragma unroll
  for (int it = 0; it < TOPK; ++it) {
    u64 gm = k[0];
    gm = dpp_min_u64<0xB1>(gm);   // quad_perm [1,0,3,2] : xor1
    gm = dpp_min_u64<0x4E>(gm);   // quad_perm [2,3,0,1] : xor2
    gm = dpp_min_u64<0x141>(gm);  // row_half_mirror    : xor7
    gm = dpp_min_u64<0x140>(gm);  // row_mirror         : xor15
    // all 16 lanes of the group now hold the group's (min key | index)

    cap = (i == it) ? (u32)gm : cap;

    if (it < TOPK - 1) {
      const bool won = (k[0] == gm);  // exactly one lane per group
#pragma unroll
      for (int j = 0; j < 15; ++j) k[j] = won ? k[j + 1] : k[j];
      k[15] = won ? ~0ull : k[15];
    }
  }

  // ---- commit zeros before atomics (same block owns the whole row) ----
  __threadfence();
  __syncthreads();

  atomicAdd(orow + i * MDIM + cap, 0.125f);
}

extern "C" void kernel_launch(void* const* d_in, const int* in_sizes, int n_in,
                              void* d_out, int out_size, void* d_ws,
                              size_t ws_size, hipStream_t stream) {
  const float* x = (const float*)d_in[0];
  const float* noise = (const float*)d_in[1];
  float* out = (float*)d_out;
  soft_topk_kernel<<<BN_TOTAL, 128, 0, stream>>>(x, noise, out);
}

// Round 10
// 194.565 us; speedup vs baseline: 4.0342x; 4.0342x over previous
//
#include <hip/hip_runtime.h>

// SoftTopK: x (8,1024,256) f32, noise (8,1024,8,256) f32
// perturbed = x + noise*1e-4 ; idx = smallest-16 indices (stable) per (b,n,s)
// out (8,1024,16,256) f32 = one_hot(idx).mean over s
//
// Block = 128 threads = 2 waves = one (b,n) row; 16-lane groups, one
// sample per group (8 samples/block). Each lane owns 16 elements
// (chunked: m = c*64 + i*4 + j -> 16B/lane coalesced loads) as packed
// u64 keys (mono(value)<<32 | m). m unique per sample => u64 order ==
// lax.top_k's stable (value asc, index asc) order, exactly.
// Per lane: Batcher odd-even mergesort of 16 keys, TEMPLATE-RECURSIVE so
// every array index is a compile-time constant (r8's loop version failed
// to fold -> scratch spill, 662us). Per round: group min of the 16 heads
// via 4 row-local DPP u64-min steps (xor1, xor2, half_mirror, mirror --
// all 16 lanes end with the min INCLUDING its index; no ballot / ffs /
// readlane / SALU round-trips); winner lane shift-pops its sorted list
// (static cndmask shift). Lane i captures rank i's index. Epilogue: LDS
// counts tile + LDS atomics + coalesced float4 store (131 MB clean
// writes vs r8's 164 MB). __fadd_rn/__fmul_rn forbid FMA contraction so
// perturbed values bit-match the fp32 reference.

#define TOPK 16
#define NSAMP 8
#define MDIM 256
#define BN_TOTAL 8192

typedef unsigned long long u64;
typedef unsigned int u32;

__device__ __forceinline__ u32 mono(float v) {
  u32 b = __float_as_uint(v);
  // monotone map: ascending u <=> ascending v (total order)
  return (b & 0x80000000u) ? ~b : (b | 0x80000000u);
}

__device__ __forceinline__ void ce(u64& a, u64& b) {
  const bool c = a < b;
  const u64 lo = c ? a : b;
  const u64 hi = c ? b : a;
  a = lo;
  b = hi;
}

// Batcher odd-even mergesort, all indices compile-time (template params).
template <int I, int END, int R, int M>
__device__ __forceinline__ void merge_ce(u64* k) {
  if constexpr (I + R < END) {
    ce(k[I], k[I + R]);
    merge_ce<I + M, END, R, M>(k);
  }
}

template <int LO, int N, int R>
__device__ __forceinline__ void oe_merge(u64* k) {
  if constexpr (2 * R < N) {
    oe_merge<LO, N, 2 * R>(k);
    oe_merge<LO + R, N, 2 * R>(k);
    merge_ce<LO + R, LO + N, R, 2 * R>(k);
  } else {
    ce(k[LO], k[LO + R]);
  }
}

template <int LO, int N>
__device__ __forceinline__ void oe_sort(u64* k) {
  if constexpr (N > 1) {
    oe_sort<LO, N / 2>(k);
    oe_sort<LO + N / 2, N / 2>(k);
    oe_merge<LO, N, 1>(k);
  }
}

template <int CTRL>
__device__ __forceinline__ u64 dpp_min_u64(u64 v) {
  const int lo = (int)(u32)v;
  const int hi = (int)(u32)(v >> 32);
  const int olo = __builtin_amdgcn_update_dpp(lo, lo, CTRL, 0xF, 0xF, false);
  const int ohi = __builtin_amdgcn_update_dpp(hi, hi, CTRL, 0xF, 0xF, false);
  const u64 o = ((u64)(u32)ohi << 32) | (u32)olo;
  return o < v ? o : v;
}

__global__ __launch_bounds__(128, 4) void soft_topk_kernel(
    const float* __restrict__ x, const float* __restrict__ noise,
    float* __restrict__ out) {
  const int bn = blockIdx.x;
  const int tid = threadIdx.x;
  const int lane = tid & 63;
  const int g = lane >> 4;            // 16-lane group within wave
  const int i = lane & 15;            // lane in group == rank it captures
  const int s = (tid >> 6) * 4 + g;   // sample 0..7

  __shared__ __align__(16) float counts[TOPK * MDIM];  // 16 KiB
  float4* const cz = reinterpret_cast<float4*>(counts);
  const float4 z4 = make_float4(0.f, 0.f, 0.f, 0.f);
#pragma unroll
  for (int j = 0; j < 8; ++j) cz[tid + 128 * j] = z4;

  // ---- build 16 packed keys: (mono(x + noise*sigma) << 32) | m ----
  // chunk c: lane i owns m = c*64 + i*4 + j  (16B/lane -> coalesced)
  const float* xrow = x + (size_t)bn * MDIM;
  const float* nrow = noise + ((size_t)bn * NSAMP + s) * MDIM;
  u64 k[16];
#pragma unroll
  for (int c = 0; c < 4; ++c) {
    const int m0 = c * 64 + i * 4;
    const float4 x4 = *reinterpret_cast<const float4*>(xrow + m0);
    const float4 n4 = *reinterpret_cast<const float4*>(nrow + m0);
    k[4 * c + 0] = ((u64)mono(__fadd_rn(x4.x, __fmul_rn(n4.x, 1e-4f))) << 32) |
                   (u32)(m0 + 0);
    k[4 * c + 1] = ((u64)mono(__fadd_rn(x4.y, __fmul_rn(n4.y, 1e-4f))) << 32) |
                   (u32)(m0 + 1);
    k[4 * c + 2] = ((u64)mono(__fadd_rn(x4.z, __fmul_rn(n4.z, 1e-4f))) << 32) |
                   (u32)(m0 + 2);
    k[4 * c + 3] = ((u64)mono(__fadd_rn(x4.w, __fmul_rn(n4.w, 1e-4f))) << 32) |
                   (u32)(m0 + 3);
  }

  // ---- per-lane sort (63 CE, fully static -> registers) ----
  oe_sort<0, 16>(k);
  __syncthreads();  // LDS zero visible before atomics below

  // ---- 16 extraction rounds: 4-step row-local DPP u64 group-min of the
  //      heads (index rides in low bits), winner shift-pops ----
  u32 cap = 0;  // m captured by lane i == rank
#pragma unroll
  for (int it = 0; it < TOPK; ++it) {
    u64 gm = k[0];
    gm = dpp_min_u64<0xB1>(gm);   // quad_perm [1,0,3,2] : pairs
    gm = dpp_min_u64<0x4E>(gm);   // quad_perm [2,3,0,1] : quads
    gm = dpp_min_u64<0x141>(gm);  // row_half_mirror    : octets
    gm = dpp_min_u64<0x140>(gm);  // row_mirror         : full 16
    // all 16 lanes of the group hold (min value | its m)

    cap = (i == it) ? (u32)gm : cap;

    if (it < TOPK - 1) {
      const bool won = (k[0] == gm);  // exactly one lane per group
#pragma unroll
      for (int j = 0; j < 15; ++j) k[j] = won ? k[j + 1] : k[j];
      k[15] = won ? ~0ull : k[15];
    }
  }

  atomicAdd(&counts[i * MDIM + cap], 0.125f);
  __syncthreads();

  // ---- write 16x256 floats, coalesced float4 ----
  float4* const outv =
      reinterpret_cast<float4*>(out + (size_t)bn * (TOPK * MDIM));
#pragma unroll
  for (int j = 0; j < 8; ++j) outv[tid + 128 * j] = cz[tid + 128 * j];
}

extern "C" void kernel_launch(void* const* d_in, const int* in_sizes, int n_in,
                              void* d_out, int out_size, void* d_ws,
                              size_t ws_size, hipStream_t stream) {
  const float* x = (const float*)d_in[0];
  const float* noise = (const float*)d_in[1];
  float* out = (float*)d_out;
  soft_topk_kernel<<<BN_TOTAL, 128, 0, stream>>>(x, noise, out);
}